// Round 8
// baseline (484.937 us; speedup 1.0000x reference)
//
#include <hip/hip_runtime.h>
#include <hip/hip_bf16.h>
#include <math.h>

// Problem constants
#define B_ 8
#define N_ 512
#define D_ 768
#define H_ 12
#define A_ 512
#define V_ 128
#define DK_ 64
#define FF_ 3072
#define P_ 1023
#define BN_TOT (B_*N_)   // 4096 rows
#define CATK (D_+V_)     // 896
#define QS_ 2304         // fused qkv row stride

typedef __attribute__((ext_vector_type(8))) short bh8;   // 8 bf16 (MFMA A/B frag)
typedef __attribute__((ext_vector_type(4))) float f4;    // MFMA C/D frag

__device__ __forceinline__ ushort f2bf(float f) {        // fp32 -> bf16 RNE
    uint x = __builtin_bit_cast(uint, f);
    uint r = (x + 0x7fffu + ((x >> 16) & 1u)) >> 16;
    return (ushort)r;
}
__device__ __forceinline__ float bf2f(ushort u) {
    return __builtin_bit_cast(float, (uint)u << 16);
}
__device__ __forceinline__ float fast_gelu(float v) {
    float t = 0.7978845608028654f * (v + 0.044715f * v * v * v);
    float e = __expf(-2.f * t);
    float th = (1.f - e) / (1.f + e);
    return 0.5f * v * (1.f + th);
}

// async global->LDS 16B (linear LDS dest; source address carries the swizzle)
#define AS1 __attribute__((address_space(1)))
#define AS3 __attribute__((address_space(3)))
__device__ __forceinline__ void gload_lds16(const void* g, void* l) {
    __builtin_amdgcn_global_load_lds((AS1 const unsigned int*)g,
                                     (AS3 unsigned int*)l, 16, 0, 0);
}

#define WAITVM(N) asm volatile("s_waitcnt vmcnt(" #N ")" ::: "memory")

// swizzled 16B chunk access into [rows][64]-ushort LDS tiles (T2 xor-swizzle)
#define STORE8(T, row, ch, val) (*(bh8*)&T[row][(((ch) ^ ((row)&7)))*8] = (val))
#define LOAD8(T, row, ch)       (*(const bh8*)&T[row][(((ch) ^ ((row)&7)))*8])

// ---------------------------------------------------------------------------
// Batched fp32 -> bf16 conversion (weights + pos_emb), 8 elems/thread
// ---------------------------------------------------------------------------
struct CvtJobs {
    const float* src[11];
    ushort*      dst[11];
    int          cum[12];   // cumulative chunk (8-elem) offsets
};
__global__ __launch_bounds__(256)
void cvt_kernel(CvtJobs J, int total)
{
    int cid = blockIdx.x * 256 + threadIdx.x;
    if (cid >= total) return;
    int j = 0;
    while (cid >= J.cum[j + 1]) ++j;
    int off = cid - J.cum[j];
    const float* s = J.src[j] + (size_t)off * 8;
    float4 f0 = *(const float4*)s;
    float4 f1 = *(const float4*)(s + 4);
    bh8 o;
    o[0] = (short)f2bf(f0.x); o[1] = (short)f2bf(f0.y);
    o[2] = (short)f2bf(f0.z); o[3] = (short)f2bf(f0.w);
    o[4] = (short)f2bf(f1.x); o[5] = (short)f2bf(f1.y);
    o[6] = (short)f2bf(f1.z); o[7] = (short)f2bf(f1.w);
    *(bh8*)(J.dst[j] + (size_t)off * 8) = o;
}

// ---------------------------------------------------------------------------
// concat([x, residual], -1) -> cat (BN, 896) bf16
// ---------------------------------------------------------------------------
__global__ __launch_bounds__(256)
void concat_kernel(const float* __restrict__ x, const float* __restrict__ res,
                   ushort* __restrict__ cat)
{
    int i = blockIdx.x * 256 + threadIdx.x;
    const int tot = BN_TOT * (CATK / 8);
    if (i >= tot) return;
    int row = i / (CATK / 8);
    int ch = i - row * (CATK / 8);
    const float* s = (ch < V_ / 8) ? (x + (size_t)row * V_ + ch * 8)
                                   : (res + (size_t)row * D_ + (ch - V_ / 8) * 8);
    float4 f0 = *(const float4*)s;
    float4 f1 = *(const float4*)(s + 4);
    bh8 o;
    o[0] = (short)f2bf(f0.x); o[1] = (short)f2bf(f0.y);
    o[2] = (short)f2bf(f0.z); o[3] = (short)f2bf(f0.w);
    o[4] = (short)f2bf(f1.x); o[5] = (short)f2bf(f1.y);
    o[6] = (short)f2bf(f1.z); o[7] = (short)f2bf(f1.w);
    *(bh8*)(cat + (size_t)row * CATK + ch * 8) = o;
}

// ---------------------------------------------------------------------------
// bf16 MFMA GEMM: C = act( X @ W^T + bias ),  X:(M,K) W:(N,K) bf16 row-major.
// Tile 128x128, BK=64, 256 thr (4 waves 2x2, 64x64 each), 16x16x32 MFMA.
// Pipeline: double-buffered LDS (64 KB), 1-deep global_load_lds prefetch,
// counted vmcnt(8) mid-loop (never 0), raw s_barrier (no full drain).
// PER-BUFFER stride = 128 rows x 128 B = 16384 B (round-7 bug: used 32768).
// bias2/bias3: if bias3 != null, bias is [bias|bias2|bias3] over D_-wide
// segments (fused qkv). Requires K%64==0, N%128==0, grid%8==0; M ragged OK.
// ---------------------------------------------------------------------------
template<int ACT, bool OUTF, bool OUTB>
__global__ __launch_bounds__(256)
void gemm_bf16(const ushort* __restrict__ Xb, const ushort* __restrict__ Wb,
               const float* __restrict__ bias, const float* __restrict__ bias2,
               const float* __restrict__ bias3, float* __restrict__ Cf,
               ushort* __restrict__ Cb, int M, int N, int K)
{
    __shared__ __align__(16) ushort As[2][128][64];   // 2 x 16 KB
    __shared__ __align__(16) ushort Bs[2][128][64];   // 2 x 16 KB

    const int tid = threadIdx.x;
    const int lane = tid & 63, w = tid >> 6;
    const int c = lane & 15, g = lane >> 4;
    const int wr = w >> 1, wc = w & 1;

    // XCD-aware bijective swizzle (gridDim.x % 8 == 0 at every call site)
    const int nwg = gridDim.x, cpx = nwg >> 3;
    const int bid = blockIdx.x;
    const int swz = (bid & 7) * cpx + (bid >> 3);
    const int nbx = N >> 7;
    const int bm = swz / nbx, bn = swz - bm * nbx;
    const int m0 = bm * 128, n0 = bn * 128;

    // staging mapping: thread -> (row str, chunk sch) per 32-row issue
    const int str = tid >> 3;
    const int sch = tid & 7;
    const int kc  = (sch ^ (str & 7)) * 8;   // pre-swizzled source chunk
    const ushort* aP[4];
    const ushort* bP[4];
#pragma unroll
    for (int i = 0; i < 4; ++i) {
        int ar = m0 + i * 32 + str; if (ar >= M) ar = M - 1;
        aP[i] = Xb + (size_t)ar * K + kc;
        bP[i] = Wb + (size_t)(n0 + i * 32 + str) * K + kc;
    }

    auto STAGE = [&](int bsel, int kt) {
        const size_t ko = (size_t)kt * 64;
#pragma unroll
        for (int i = 0; i < 4; ++i) {
            gload_lds16(aP[i] + ko, (char*)As + bsel * 16384 + i * 4096 + tid * 16);
            gload_lds16(bP[i] + ko, (char*)Bs + bsel * 16384 + i * 4096 + tid * 16);
        }
    };

    f4 acc[4][4];
#pragma unroll
    for (int mt = 0; mt < 4; ++mt)
#pragma unroll
        for (int nt = 0; nt < 4; ++nt) acc[mt][nt] = (f4){0.f, 0.f, 0.f, 0.f};

    const int ntile = K >> 6;
    STAGE(0, 0);

    for (int kt = 0; kt < ntile; ++kt) {
        const int cur = kt & 1;
        if (kt + 1 < ntile) {
            STAGE(cur ^ 1, kt + 1);
            WAITVM(8);                        // tile kt's 8 loads done
        } else {
            WAITVM(0);
        }
        __builtin_amdgcn_s_barrier();         // raw: no implicit full drain
        __builtin_amdgcn_sched_barrier(0);

#pragma unroll
        for (int ks = 0; ks < 2; ++ks) {
            bh8 af[4], bfr[4];
#pragma unroll
            for (int mt = 0; mt < 4; ++mt)
                af[mt] = LOAD8(As[cur], wr * 64 + mt * 16 + c, ks * 4 + g);
#pragma unroll
            for (int nt = 0; nt < 4; ++nt)
                bfr[nt] = LOAD8(Bs[cur], wc * 64 + nt * 16 + c, ks * 4 + g);
#pragma unroll
            for (int mt = 0; mt < 4; ++mt)
#pragma unroll
                for (int nt = 0; nt < 4; ++nt)
                    acc[mt][nt] = __builtin_amdgcn_mfma_f32_16x16x32_bf16(
                        af[mt], bfr[nt], acc[mt][nt], 0, 0, 0);
        }

        if (kt + 1 < ntile) {
            asm volatile("s_waitcnt lgkmcnt(0)" ::: "memory");  // own reads done
            __builtin_amdgcn_s_barrier();     // cur buffer overwritten next iter
        }
    }

    // epilogue: D layout col = lane&15, row = (lane>>4)*4 + reg
    const int rowb = m0 + wr * 64 + g * 4;
    const int colb = n0 + wc * 64 + c;
#pragma unroll
    for (int nt = 0; nt < 4; ++nt) {
        const int n = colb + nt * 16;
        float bb = 0.f;
        if (bias3) {
            bb = (n < D_) ? bias[n] : (n < 2 * D_) ? bias2[n - D_] : bias3[n - 2 * D_];
        } else if (bias) {
            bb = bias[n];
        }
#pragma unroll
        for (int mt = 0; mt < 4; ++mt) {
#pragma unroll
            for (int r = 0; r < 4; ++r) {
                const int m = rowb + mt * 16 + r;
                if (m < M) {
                    float vv = acc[mt][nt][r] + bb;
                    if (ACT == 1) vv = fast_gelu(vv);
                    const size_t off = (size_t)m * N + n;
                    if (OUTF) Cf[off] = vv;
                    if (OUTB) Cb[off] = f2bf(vv);
                }
            }
        }
    }
}

// ---------------------------------------------------------------------------
// Fused rel-pos flash attention, bf16 in / bf16 out, fp32 softmax.
// (unchanged — isolating the GEMM change)
// ---------------------------------------------------------------------------
__global__ __launch_bounds__(256)
void attn_mfma_kernel(const ushort* __restrict__ qkv,
                      const ushort* __restrict__ pg,
                      const float* __restrict__ bu, const float* __restrict__ bv,
                      ushort* __restrict__ ctx)
{
    const int tid  = threadIdx.x;
    const int lane = tid & 63, w = tid >> 6;
    const int c = lane & 15, g = lane >> 4;
    const int qt = blockIdx.x >> 6, bh = blockIdx.x & 63;
    const int h = bh % H_, b = bh / H_;
    const int q0 = qt * 64;

    const ushort* qg = qkv;
    const ushort* kg = qkv + D_;
    const ushort* vg = qkv + 2 * D_;

    __shared__ __align__(16) ushort Kt[64][64];
    __shared__ __align__(16) ushort Vt[64][64];    // transposed: [d][k]
    __shared__ __align__(16) ushort Pt[128][64];
    __shared__ __align__(16) ushort SW[4][16][88]; // 176B rows: conflict-padded
    __shared__ float a_s[4][16], l_s[4][16];

    // ---- Q fragments in registers (lane owns q-row 16w+c, chunks g, g+4) ----
    bh8 aqu0, aqu1, aqv0, aqv1;
    {
        const ushort* qrow = qg + (size_t)(b * N_ + q0 + 16 * w + c) * QS_ + h * DK_;
        const float* buh = bu + h * DK_;
        const float* bvh = bv + h * DK_;
        bh8 qa = *(const bh8*)(qrow + g * 8);
        bh8 qb = *(const bh8*)(qrow + (g + 4) * 8);
        float4 ua0 = *(const float4*)(buh + g * 8);
        float4 ua1 = *(const float4*)(buh + g * 8 + 4);
        float4 ub0 = *(const float4*)(buh + (g + 4) * 8);
        float4 ub1 = *(const float4*)(buh + (g + 4) * 8 + 4);
        float4 va0 = *(const float4*)(bvh + g * 8);
        float4 va1 = *(const float4*)(bvh + g * 8 + 4);
        float4 vb0 = *(const float4*)(bvh + (g + 4) * 8);
        float4 vb1 = *(const float4*)(bvh + (g + 4) * 8 + 4);
        float ua[8] = {ua0.x, ua0.y, ua0.z, ua0.w, ua1.x, ua1.y, ua1.z, ua1.w};
        float ub[8] = {ub0.x, ub0.y, ub0.z, ub0.w, ub1.x, ub1.y, ub1.z, ub1.w};
        float va[8] = {va0.x, va0.y, va0.z, va0.w, va1.x, va1.y, va1.z, va1.w};
        float vb[8] = {vb0.x, vb0.y, vb0.z, vb0.w, vb1.x, vb1.y, vb1.z, vb1.w};
#pragma unroll
        for (int e = 0; e < 8; ++e) {
            float fa = bf2f((ushort)qa[e]);
            float fb = bf2f((ushort)qb[e]);
            aqu0[e] = (short)f2bf(fa + ua[e]);
            aqu1[e] = (short)f2bf(fb + ub[e]);
            aqv0[e] = (short)f2bf(fa + va[e]);
            aqv1[e] = (short)f2bf(fb + vb[e]);
        }
    }

    float m_run[4] = {-1e30f, -1e30f, -1e30f, -1e30f};
    float l_run[4] = {0.f, 0.f, 0.f, 0.f};

    f4 ctxa[4];
#pragma unroll
    for (int dt = 0; dt < 4; ++dt) ctxa[dt] = (f4){0.f, 0.f, 0.f, 0.f};

    const int str = tid >> 3;   // 0..31 (gload staging row)
    const int sch = tid & 7;

    for (int t = 0; t < 8; ++t) {
        const int k0 = t * 64;
        if (t) __syncthreads();   // prior tile's LDS reads done

        // ---- K tile via global_load_lds (pre-swizzled source) ----
#pragma unroll
        for (int i = 0; i < 2; ++i) {
            const int r = i * 32 + str;
            const ushort* src = kg + (size_t)(b * N_ + k0 + r) * QS_ + h * DK_
                                + ((sch ^ (r & 7)) * 8);
            gload_lds16(src, (char*)Kt + r * 128 + sch * 16);
        }
        // ---- P window via global_load_lds ----
        {
            const int wbase = k0 + 448 - q0;
#pragma unroll
            for (int i = 0; i < 4; ++i) {
                const int r = i * 32 + str;
                int j = wbase + r; if (j > 1022) j = 1022;
                const ushort* src = pg + (size_t)j * D_ + h * DK_
                                    + ((sch ^ (r & 7)) * 8);
                gload_lds16(src, (char*)Pt + r * 128 + sch * 16);
            }
        }
        // ---- V^T tile: wave w covers chunks w*2,w*2+1 for row = lane ----
        {
            const ushort* vrow = vg + (size_t)(b * N_ + k0 + lane) * QS_ + h * DK_;
#pragma unroll
            for (int half = 0; half < 2; ++half) {
                const int ch = w * 2 + half;
                bh8 v8 = *(const bh8*)(vrow + ch * 8);
#pragma unroll
                for (int e = 0; e < 8; ++e) {
                    const int db = ch * 8 + e;
                    Vt[db][(((lane >> 3) ^ (db & 7)) << 3) | (lane & 7)] = (ushort)v8[e];
                }
            }
        }
        __syncthreads();

        // ---- bd_tilde[q][j] = Qv . P over wave's 80-wide window ----
        const int joff = 48 - 16 * w;
#pragma unroll
        for (int jt = 0; jt < 5; ++jt) {
            const int jb = joff + jt * 16;
            bh8 p0 = LOAD8(Pt, jb + c, g);
            bh8 p1 = LOAD8(Pt, jb + c, g + 4);
            f4 acc = (f4){0.f, 0.f, 0.f, 0.f};
            acc = __builtin_amdgcn_mfma_f32_16x16x32_bf16(aqv0, p0, acc, 0, 0, 0);
            acc = __builtin_amdgcn_mfma_f32_16x16x32_bf16(aqv1, p1, acc, 0, 0, 0);
#pragma unroll
            for (int r = 0; r < 4; ++r)
                SW[w][4 * g + r][jt * 16 + c] = f2bf(acc[r]);
        }

        // ---- ac = Qu . K^T ----
        f4 S[4];
#pragma unroll
        for (int kt = 0; kt < 4; ++kt) {
            bh8 k0f = LOAD8(Kt, kt * 16 + c, g);
            bh8 k1f = LOAD8(Kt, kt * 16 + c, g + 4);
            f4 acc = (f4){0.f, 0.f, 0.f, 0.f};
            acc = __builtin_amdgcn_mfma_f32_16x16x32_bf16(aqu0, k0f, acc, 0, 0, 0);
            acc = __builtin_amdgcn_mfma_f32_16x16x32_bf16(aqu1, k1f, acc, 0, 0, 0);
            S[kt] = acc;
        }

        // ---- rel-shift apply + scale ----
#pragma unroll
        for (int kt = 0; kt < 4; ++kt)
#pragma unroll
            for (int r = 0; r < 4; ++r) {
                const int qloc = 4 * g + r;
                const int kloc = kt * 16 + c;
                S[kt][r] = (S[kt][r] + bf2f(SW[w][qloc][kloc - qloc + 15])) * 0.125f;
            }

        // ---- online softmax (m/l in registers) ----
        float mx[4], al[4];
#pragma unroll
        for (int r = 0; r < 4; ++r) {
            float t1 = fmaxf(fmaxf(S[0][r], S[1][r]), fmaxf(S[2][r], S[3][r]));
            t1 = fmaxf(t1, __shfl_xor(t1, 1));
            t1 = fmaxf(t1, __shfl_xor(t1, 2));
            t1 = fmaxf(t1, __shfl_xor(t1, 4));
            t1 = fmaxf(t1, __shfl_xor(t1, 8));
            mx[r] = t1;
        }
#pragma unroll
        for (int r = 0; r < 4; ++r) {
            float mn = fmaxf(m_run[r], mx[r]);
            al[r] = __expf(m_run[r] - mn);
            m_run[r] = mn;
        }
#pragma unroll
        for (int kt = 0; kt < 4; ++kt)
#pragma unroll
            for (int r = 0; r < 4; ++r)
                S[kt][r] = __expf(S[kt][r] - m_run[r]);
        float ts[4];
#pragma unroll
        for (int r = 0; r < 4; ++r) {
            float s1 = (S[0][r] + S[1][r]) + (S[2][r] + S[3][r]);
            s1 += __shfl_xor(s1, 1);
            s1 += __shfl_xor(s1, 2);
            s1 += __shfl_xor(s1, 4);
            s1 += __shfl_xor(s1, 8);
            ts[r] = s1;
            l_run[r] = l_run[r] * al[r] + s1;
        }
        if (c == 0) {
#pragma unroll
            for (int r = 0; r < 4; ++r) a_s[w][4 * g + r] = al[r];
        }
        // ---- P_attn (bf16) into SW cols 0..63 ----
#pragma unroll
        for (int kt = 0; kt < 4; ++kt)
#pragma unroll
            for (int r = 0; r < 4; ++r)
                SW[w][4 * g + r][kt * 16 + c] = f2bf(S[kt][r]);

        // ---- ctx^T += V^T @ P_attn^T, online rescale ----
        const float af = a_s[w][c];   // alpha of this lane's ctx column (q=c)
#pragma unroll
        for (int dt = 0; dt < 4; ++dt)
#pragma unroll
            for (int r = 0; r < 4; ++r)
                ctxa[dt][r] *= af;
#pragma unroll
        for (int kcc = 0; kcc < 2; ++kcc) {
            bh8 pb8 = *(const bh8*)&SW[w][c][(kcc * 4 + g) * 8];
#pragma unroll
            for (int dt = 0; dt < 4; ++dt) {
                bh8 av = LOAD8(Vt, dt * 16 + c, kcc * 4 + g);
                ctxa[dt] = __builtin_amdgcn_mfma_f32_16x16x32_bf16(av, pb8, ctxa[dt], 0, 0, 0);
            }
        }
    }

    // ---- epilogue: ctx[q][d] = ctx^T / l  (bf16) ----
    if (c == 0) {
#pragma unroll
        for (int r = 0; r < 4; ++r) l_s[w][4 * g + r] = l_run[r];
    }
    const float linv = 1.f / l_s[w][c];
    const int qgl = q0 + 16 * w + c;
    ushort* crow = ctx + ((size_t)(b * N_ + qgl) * D_ + h * DK_);
#pragma unroll
    for (int dt = 0; dt < 4; ++dt)
#pragma unroll
        for (int r = 0; r < 4; ++r)
            crow[dt * 16 + 4 * g + r] = f2bf(ctxa[dt][r] * linv);
}

// ---------------------------------------------------------------------------
// out = LayerNorm(a + b) * g + beta ; optional bf16 copy
// ---------------------------------------------------------------------------
template<bool OUTB>
__global__ __launch_bounds__(256)
void add_ln_kernel(const float* __restrict__ a, const float* __restrict__ b,
                   const float* __restrict__ g, const float* __restrict__ beta,
                   float* __restrict__ out, ushort* __restrict__ outb)
{
    const int row = blockIdx.x;
    const int tid = threadIdx.x;
    const int lane = tid & 63, wave = tid >> 6;
    __shared__ float red[8];

    const float* ar = a + (size_t)row * D_;
    const float* br = b + (size_t)row * D_;
    float v0 = ar[tid]       + br[tid];
    float v1 = ar[tid + 256] + br[tid + 256];
    float v2 = ar[tid + 512] + br[tid + 512];

    float s = v0 + v1 + v2;
#pragma unroll
    for (int off = 32; off; off >>= 1) s += __shfl_xor(s, off);
    if (lane == 0) red[wave] = s;
    __syncthreads();
    const float mean = (red[0] + red[1] + red[2] + red[3]) * (1.f / 768.f);

    float d0 = v0 - mean, d1 = v1 - mean, d2 = v2 - mean;
    float vs = d0 * d0 + d1 * d1 + d2 * d2;
#pragma unroll
    for (int off = 32; off; off >>= 1) vs += __shfl_xor(vs, off);
    if (lane == 0) red[4 + wave] = vs;
    __syncthreads();
    const float var = (red[4] + red[5] + red[6] + red[7]) * (1.f / 768.f);
    const float inv = rsqrtf(var + 1e-5f);

    float r0 = d0 * inv * g[tid]       + beta[tid];
    float r1 = d1 * inv * g[tid + 256] + beta[tid + 256];
    float r2 = d2 * inv * g[tid + 512] + beta[tid + 512];
    float* orow = out + (size_t)row * D_;
    orow[tid] = r0; orow[tid + 256] = r1; orow[tid + 512] = r2;
    if (OUTB) {
        ushort* brow = outb + (size_t)row * D_;
        brow[tid] = f2bf(r0); brow[tid + 256] = f2bf(r1); brow[tid + 512] = f2bf(r2);
    }
}

// ---------------------------------------------------------------------------
extern "C" void kernel_launch(void* const* d_in, const int* in_sizes, int n_in,
                              void* d_out, int out_size, void* d_ws, size_t ws_size,
                              hipStream_t stream)
{
    const float* x         = (const float*)d_in[0];
    const float* pos_emb   = (const float*)d_in[2];
    const float* residual  = (const float*)d_in[3];
    const float* fuse_W    = (const float*)d_in[5];
    const float* fuse_b    = (const float*)d_in[6];
    const float* posproj_W = (const float*)d_in[7];
    const float* posproj_b = (const float*)d_in[8];
    const float* Wq        = (const float*)d_in[9];
    const float* bq        = (const float*)d_in[10];
    const float* Wk        = (const float*)d_in[11];
    const float* bk        = (const float*)d_in[12];
    const float* Wv        = (const float*)d_in[13];
    const float* bv        = (const float*)d_in[14];
    const float* Wout      = (const float*)d_in[15];
    const float* bout      = (const float*)d_in[16];
    const float* Wpos      = (const float*)d_in[17];
    const float* pbu       = (const float*)d_in[18];
    const float* pbv       = (const float*)d_in[19];
    const float* ln1_g     = (const float*)d_in[20];
    const float* ln1_b     = (const float*)d_in[21];
    const float* Wi        = (const float*)d_in[22];
    const float* bi        = (const float*)d_in[23];
    const float* Wo        = (const float*)d_in[24];
    const float* bo        = (const float*)d_in[25];
    const float* ln2_g     = (const float*)d_in[26];
    const float* ln2_b     = (const float*)d_in[27];
    const float* Wac       = (const float*)d_in[28];
    const float* bac       = (const float*)d_in[29];

    // ---- workspace carve (bytes, 256-aligned) ----
    char* base = (char*)d_ws;
    auto alloc = [&](size_t bytes) {
        char* p = base; base += (bytes + 255) & ~(size_t)255; return p;
    };
    float*  h     = (float*) alloc((size_t)BN_TOT * D_ * 4);
    float*  h1    = (float*) alloc((size_t)BN_TOT * D_ * 4);
    float*  aoff2 = (float*) alloc((size_t)BN_TOT * D_ * 4);   // attn_out / ff2
    ushort* big   = (ushort*)alloc((size_t)BN_TOT * FF_ * 2);  // catb / ff1b
    ushort* hb    = (ushort*)alloc((size_t)BN_TOT * D_ * 2);
    ushort* qkvb  = (ushort*)alloc((size_t)BN_TOT * QS_ * 2);  // fused q|k|v
    ushort* ctxb  = (ushort*)alloc((size_t)BN_TOT * D_ * 2);
    ushort* h1b   = (ushort*)alloc((size_t)BN_TOT * D_ * 2);
    ushort* h2b   = (ushort*)alloc((size_t)BN_TOT * D_ * 2);
    ushort* peb   = (ushort*)alloc((size_t)P_ * D_ * 2);
    ushort* pbb   = (ushort*)alloc((size_t)P_ * D_ * 2);
    ushort* posb  = (ushort*)alloc((size_t)P_ * A_ * 2);
    ushort* wfuse = (ushort*)alloc((size_t)D_ * CATK * 2);
    ushort* wpp   = (ushort*)alloc((size_t)D_ * A_ * 2);
    ushort* wqkv  = (ushort*)alloc((size_t)QS_ * D_ * 2);      // Wq|Wk|Wv rows
    ushort* wout  = (ushort*)alloc((size_t)D_ * D_ * 2);
    ushort* wpos  = (ushort*)alloc((size_t)D_ * D_ * 2);
    ushort* wi    = (ushort*)alloc((size_t)FF_ * D_ * 2);
    ushort* wo    = (ushort*)alloc((size_t)D_ * FF_ * 2);
    ushort* wac   = (ushort*)alloc((size_t)A_ * D_ * 2);
    ushort* catb  = big;   // dead after fuse GEMM
    ushort* ff1b  = big;

    float* out_ac = (float*)d_out;
    float* h2     = out_ac + (size_t)BN_TOT * A_;

    dim3 blk(256);

    // ---- 0. convert weights + pos_emb to bf16 (Wq/Wk/Wv stacked = wqkv) ----
    {
        CvtJobs J;
        const float* s[11] = {fuse_W, posproj_W, Wq, Wk, Wv, Wout, Wpos, Wi, Wo, Wac, pos_emb};
        ushort* d[11] = {wfuse, wpp, wqkv, wqkv + (size_t)D_*D_, wqkv + (size_t)2*D_*D_,
                         wout, wpos, wi, wo, wac, posb};
        int n[11] = {D_*CATK, D_*A_, D_*D_, D_*D_, D_*D_, D_*D_, D_*D_, FF_*D_, D_*FF_, A_*D_, P_*A_};
        int cum = 0;
        for (int j = 0; j < 11; ++j) {
            J.src[j] = s[j]; J.dst[j] = d[j]; J.cum[j] = cum; cum += n[j] / 8;
        }
        J.cum[11] = cum;
        cvt_kernel<<<(cum + 255) / 256, blk, 0, stream>>>(J, cum);
    }
    // ---- 1. concat -> catb (bf16) ----
    concat_kernel<<<(BN_TOT * (CATK / 8) + 255) / 256, blk, 0, stream>>>(x, residual, catb);
    // ---- 2. h = cat @ fuse_W^T + b  (f32 + bf16) ----
    gemm_bf16<0, true, true><<<dim3((BN_TOT/128) * (D_/128)), blk, 0, stream>>>(
        catb, wfuse, fuse_b, nullptr, nullptr, h, hb, BN_TOT, D_, CATK);
    // ---- 3. pe = pos_emb @ posproj^T + b  (bf16) ----
    gemm_bf16<0, false, true><<<dim3(8 * (D_/128)), blk, 0, stream>>>(
        posb, wpp, posproj_b, nullptr, nullptr, nullptr, peb, P_, D_, A_);
    // ---- 4. qkv = h @ [Wq|Wk|Wv]^T + [bq|bk|bv]  (bf16, N=2304) ----
    gemm_bf16<0, false, true><<<dim3((BN_TOT/128) * (QS_/128)), blk, 0, stream>>>(
        hb, wqkv, bq, bk, bv, nullptr, qkvb, BN_TOT, QS_, D_);
    // ---- 5. p = pe @ Wpos^T  (bf16) ----
    gemm_bf16<0, false, true><<<dim3(8 * (D_/128)), blk, 0, stream>>>(
        peb, wpos, nullptr, nullptr, nullptr, nullptr, pbb, P_, D_, D_);
    // ---- 6. fused attention -> ctxb (bf16) ----
    attn_mfma_kernel<<<dim3(B_ * H_ * 8), blk, 0, stream>>>(
        qkvb, pbb, pbu, pbv, ctxb);
    // ---- 7. attn_out = ctx @ Wout^T + b  (f32) ----
    gemm_bf16<0, true, false><<<dim3((BN_TOT/128) * (D_/128)), blk, 0, stream>>>(
        ctxb, wout, bout, nullptr, nullptr, aoff2, nullptr, BN_TOT, D_, D_);
    // ---- 8. h1 = LN(attn_out + h)  (f32 + bf16) ----
    add_ln_kernel<true><<<BN_TOT, blk, 0, stream>>>(aoff2, h, ln1_g, ln1_b, h1, h1b);
    // ---- 9. ff1 = gelu(h1 @ Wi^T + bi)  (bf16) ----
    gemm_bf16<1, false, true><<<dim3((BN_TOT/128) * (FF_/128)), blk, 0, stream>>>(
        h1b, wi, bi, nullptr, nullptr, nullptr, ff1b, BN_TOT, FF_, D_);
    // ---- 10. ff2 = ff1 @ Wo^T + bo  (f32) ----
    gemm_bf16<0, true, false><<<dim3((BN_TOT/128) * (D_/128)), blk, 0, stream>>>(
        ff1b, wo, bo, nullptr, nullptr, aoff2, nullptr, BN_TOT, D_, FF_);
    // ---- 11. h2 = LN(ff2 + h1) -> d_out (+bf16) ----
    add_ln_kernel<true><<<BN_TOT, blk, 0, stream>>>(aoff2, h1, ln2_g, ln2_b, h2, h2b);
    // ---- 12. out_ac = h2 @ Wac^T + bac -> d_out ----
    gemm_bf16<0, true, false><<<dim3((BN_TOT/128) * (A_/128)), blk, 0, stream>>>(
        h2b, wac, bac, nullptr, nullptr, out_ac, nullptr, BN_TOT, A_, D_);
}

// Round 9
// 406.697 us; speedup vs baseline: 1.1924x; 1.1924x over previous
//
#include <hip/hip_runtime.h>
#include <hip/hip_bf16.h>
#include <math.h>

// Problem constants
#define B_ 8
#define N_ 512
#define D_ 768
#define H_ 12
#define A_ 512
#define V_ 128
#define DK_ 64
#define FF_ 3072
#define P_ 1023
#define BN_TOT (B_*N_)   // 4096 rows
#define CATK (D_+V_)     // 896
#define QS_ 2304         // fused qkv row stride

typedef __attribute__((ext_vector_type(8))) short bh8;   // 8 bf16 (MFMA A/B frag)
typedef __attribute__((ext_vector_type(4))) float f4;    // MFMA C/D frag

__device__ __forceinline__ ushort f2bf(float f) {        // fp32 -> bf16 RNE
    uint x = __builtin_bit_cast(uint, f);
    uint r = (x + 0x7fffu + ((x >> 16) & 1u)) >> 16;
    return (ushort)r;
}
__device__ __forceinline__ float bf2f(ushort u) {
    return __builtin_bit_cast(float, (uint)u << 16);
}
__device__ __forceinline__ float fast_gelu(float v) {
    float t = 0.7978845608028654f * (v + 0.044715f * v * v * v);
    float e = __expf(-2.f * t);
    float th = (1.f - e) / (1.f + e);
    return 0.5f * v * (1.f + th);
}

// async global->LDS 16B (linear LDS dest; source address carries the swizzle)
#define AS1 __attribute__((address_space(1)))
#define AS3 __attribute__((address_space(3)))
__device__ __forceinline__ void gload_lds16(const void* g, void* l) {
    __builtin_amdgcn_global_load_lds((AS1 const unsigned int*)g,
                                     (AS3 unsigned int*)l, 16, 0, 0);
}

// swizzled 16B chunk access into [rows][64]-ushort LDS tiles (T2 xor-swizzle)
#define LOAD8(T, row, ch)       (*(const bh8*)&T[row][(((ch) ^ ((row)&7)))*8])

// ---------------------------------------------------------------------------
// Batched fp32 -> bf16 conversion (weights + pos_emb), 8 elems/thread
// ---------------------------------------------------------------------------
struct CvtJobs {
    const float* src[11];
    ushort*      dst[11];
    int          cum[12];   // cumulative chunk (8-elem) offsets
};
__global__ __launch_bounds__(256)
void cvt_kernel(CvtJobs J, int total)
{
    int cid = blockIdx.x * 256 + threadIdx.x;
    if (cid >= total) return;
    int j = 0;
    while (cid >= J.cum[j + 1]) ++j;
    int off = cid - J.cum[j];
    const float* s = J.src[j] + (size_t)off * 8;
    float4 f0 = *(const float4*)s;
    float4 f1 = *(const float4*)(s + 4);
    bh8 o;
    o[0] = (short)f2bf(f0.x); o[1] = (short)f2bf(f0.y);
    o[2] = (short)f2bf(f0.z); o[3] = (short)f2bf(f0.w);
    o[4] = (short)f2bf(f1.x); o[5] = (short)f2bf(f1.y);
    o[6] = (short)f2bf(f1.z); o[7] = (short)f2bf(f1.w);
    *(bh8*)(J.dst[j] + (size_t)off * 8) = o;
}

// ---------------------------------------------------------------------------
// concat([x, residual], -1) -> cat (BN, 896) bf16
// ---------------------------------------------------------------------------
__global__ __launch_bounds__(256)
void concat_kernel(const float* __restrict__ x, const float* __restrict__ res,
                   ushort* __restrict__ cat)
{
    int i = blockIdx.x * 256 + threadIdx.x;
    const int tot = BN_TOT * (CATK / 8);
    if (i >= tot) return;
    int row = i / (CATK / 8);
    int ch = i - row * (CATK / 8);
    const float* s = (ch < V_ / 8) ? (x + (size_t)row * V_ + ch * 8)
                                   : (res + (size_t)row * D_ + (ch - V_ / 8) * 8);
    float4 f0 = *(const float4*)s;
    float4 f1 = *(const float4*)(s + 4);
    bh8 o;
    o[0] = (short)f2bf(f0.x); o[1] = (short)f2bf(f0.y);
    o[2] = (short)f2bf(f0.z); o[3] = (short)f2bf(f0.w);
    o[4] = (short)f2bf(f1.x); o[5] = (short)f2bf(f1.y);
    o[6] = (short)f2bf(f1.z); o[7] = (short)f2bf(f1.w);
    *(bh8*)(cat + (size_t)row * CATK + ch * 8) = o;
}

// ---------------------------------------------------------------------------
// bf16 MFMA GEMM: C = act( X @ W^T + bias ),  X:(M,K) W:(N,K) bf16 row-major.
// Tile 128x128, BK=64, 256 thr (4 waves 2x2), single-buffered LDS 32KB
// (>=3 blocks/CU -> implicit wave-level overlap; round-5 validated structure).
// SPLITK>1: grid = tiles*SPLITK; slice s computes K-range [s*K/SPLITK, ...)
// and writes raw f32 partials to Cf + s*M*N (no bias/act).
// bias2/bias3 (SPLITK==1 only): concat [bias|bias2|bias3] D_-wide (fused qkv).
// Requires K%(64*SPLITK)==0, N%128==0, grid%8==0; M ragged OK.
// ---------------------------------------------------------------------------
template<int ACT, bool OUTF, bool OUTB, int SPLITK>
__global__ __launch_bounds__(256)
void gemm_bf16(const ushort* __restrict__ Xb, const ushort* __restrict__ Wb,
               const float* __restrict__ bias, const float* __restrict__ bias2,
               const float* __restrict__ bias3, float* __restrict__ Cf,
               ushort* __restrict__ Cb, int M, int N, int K)
{
    __shared__ __align__(16) ushort As[128][64];   // 16 KB
    __shared__ __align__(16) ushort Bs[128][64];   // 16 KB

    const int tid = threadIdx.x;
    const int lane = tid & 63, w = tid >> 6;
    const int c = lane & 15, g = lane >> 4;
    const int wr = w >> 1, wc = w & 1;

    // XCD-aware bijective swizzle (gridDim.x % 8 == 0 at every call site)
    const int nwg = gridDim.x, cpx = nwg >> 3;
    const int bid = blockIdx.x;
    const int swz = (bid & 7) * cpx + (bid >> 3);
    const int tiles = nwg / SPLITK;
    const int slice = swz / tiles;
    const int t = swz - slice * tiles;
    const int nbx = N >> 7;
    const int bm = t / nbx, bn = t - bm * nbx;
    const int m0 = bm * 128, n0 = bn * 128;
    const int Ks = K / SPLITK;
    const int kbeg = slice * Ks;

    // staging mapping: thread -> (row str, chunk sch) per 32-row issue
    const int str = tid >> 3;
    const int sch = tid & 7;
    const int kc  = (sch ^ (str & 7)) * 8;   // pre-swizzled source chunk
    const ushort* aP[4];
    const ushort* bP[4];
#pragma unroll
    for (int i = 0; i < 4; ++i) {
        int ar = m0 + i * 32 + str; if (ar >= M) ar = M - 1;
        aP[i] = Xb + (size_t)ar * K + kc + kbeg;
        bP[i] = Wb + (size_t)(n0 + i * 32 + str) * K + kc + kbeg;
    }

    f4 acc[4][4];
#pragma unroll
    for (int mt = 0; mt < 4; ++mt)
#pragma unroll
        for (int nt = 0; nt < 4; ++nt) acc[mt][nt] = (f4){0.f, 0.f, 0.f, 0.f};

    for (int k0 = 0; k0 < Ks; k0 += 64) {
        if (k0) __syncthreads();   // everyone done reading previous tile
#pragma unroll
        for (int i = 0; i < 4; ++i) {
            gload_lds16(aP[i] + k0, (char*)As + i * 4096 + tid * 16);
            gload_lds16(bP[i] + k0, (char*)Bs + i * 4096 + tid * 16);
        }
        __syncthreads();           // implicit vmcnt(0): staging complete
#pragma unroll
        for (int ks = 0; ks < 2; ++ks) {
            bh8 af[4], bfr[4];
#pragma unroll
            for (int mt = 0; mt < 4; ++mt)
                af[mt] = LOAD8(As, wr * 64 + mt * 16 + c, ks * 4 + g);
#pragma unroll
            for (int nt = 0; nt < 4; ++nt)
                bfr[nt] = LOAD8(Bs, wc * 64 + nt * 16 + c, ks * 4 + g);
#pragma unroll
            for (int mt = 0; mt < 4; ++mt)
#pragma unroll
                for (int nt = 0; nt < 4; ++nt)
                    acc[mt][nt] = __builtin_amdgcn_mfma_f32_16x16x32_bf16(
                        af[mt], bfr[nt], acc[mt][nt], 0, 0, 0);
        }
    }

    // epilogue: D layout col = lane&15, row = (lane>>4)*4 + reg
    const int rowb = m0 + wr * 64 + g * 4;
    const int colb = n0 + wc * 64 + c;
    if (SPLITK > 1) {
        float* Cp = Cf + (size_t)slice * M * N;
#pragma unroll
        for (int nt = 0; nt < 4; ++nt) {
            const int n = colb + nt * 16;
#pragma unroll
            for (int mt = 0; mt < 4; ++mt)
#pragma unroll
                for (int r = 0; r < 4; ++r)
                    Cp[(size_t)(rowb + mt * 16 + r) * N + n] = acc[mt][nt][r];
        }
        return;
    }
#pragma unroll
    for (int nt = 0; nt < 4; ++nt) {
        const int n = colb + nt * 16;
        float bb = 0.f;
        if (bias3) {
            bb = (n < D_) ? bias[n] : (n < 2 * D_) ? bias2[n - D_] : bias3[n - 2 * D_];
        } else if (bias) {
            bb = bias[n];
        }
#pragma unroll
        for (int mt = 0; mt < 4; ++mt) {
#pragma unroll
            for (int r = 0; r < 4; ++r) {
                const int m = rowb + mt * 16 + r;
                if (m < M) {
                    float vv = acc[mt][nt][r] + bb;
                    if (ACT == 1) vv = fast_gelu(vv);
                    const size_t off = (size_t)m * N + n;
                    if (OUTF) Cf[off] = vv;
                    if (OUTB) Cb[off] = f2bf(vv);
                }
            }
        }
    }
}

// ---------------------------------------------------------------------------
// reduce2: out = p[0..] + p[stride..] + bias[col]  (f32 and/or bf16 outputs)
// ---------------------------------------------------------------------------
template<bool WF, bool WB>
__global__ __launch_bounds__(256)
void reduce2_kernel(const float* __restrict__ p, size_t pstride,
                    const float* __restrict__ bias, int ncols,
                    float* of, ushort* ob, int total8)
{
    int i = blockIdx.x * 256 + threadIdx.x;
    if (i >= total8) return;
    size_t base = (size_t)i * 8;
    int col = (int)(base % (size_t)ncols);
    const float* p0 = p + base;
    const float* p1 = p + pstride + base;
    float4 a0 = *(const float4*)p0,        a1 = *(const float4*)(p0 + 4);
    float4 b0 = *(const float4*)p1,        b1 = *(const float4*)(p1 + 4);
    float4 c0 = *(const float4*)(bias + col), c1 = *(const float4*)(bias + col + 4);
    float r[8] = {a0.x + b0.x + c0.x, a0.y + b0.y + c0.y,
                  a0.z + b0.z + c0.z, a0.w + b0.w + c0.w,
                  a1.x + b1.x + c1.x, a1.y + b1.y + c1.y,
                  a1.z + b1.z + c1.z, a1.w + b1.w + c1.w};
    if (WF) {
        *(float4*)(of + base)     = (float4){r[0], r[1], r[2], r[3]};
        *(float4*)(of + base + 4) = (float4){r[4], r[5], r[6], r[7]};
    }
    if (WB) {
        bh8 o;
#pragma unroll
        for (int e = 0; e < 8; ++e) o[e] = (short)f2bf(r[e]);
        *(bh8*)(ob + base) = o;
    }
}

// ---------------------------------------------------------------------------
// Fused rel-pos flash attention, bf16 in / bf16 out, fp32 softmax. (unchanged)
// ---------------------------------------------------------------------------
__global__ __launch_bounds__(256)
void attn_mfma_kernel(const ushort* __restrict__ qkv,
                      const ushort* __restrict__ pg,
                      const float* __restrict__ bu, const float* __restrict__ bv,
                      ushort* __restrict__ ctx)
{
    const int tid  = threadIdx.x;
    const int lane = tid & 63, w = tid >> 6;
    const int c = lane & 15, g = lane >> 4;
    const int qt = blockIdx.x >> 6, bh = blockIdx.x & 63;
    const int h = bh % H_, b = bh / H_;
    const int q0 = qt * 64;

    const ushort* qg = qkv;
    const ushort* kg = qkv + D_;
    const ushort* vg = qkv + 2 * D_;

    __shared__ __align__(16) ushort Kt[64][64];
    __shared__ __align__(16) ushort Vt[64][64];    // transposed: [d][k]
    __shared__ __align__(16) ushort Pt[128][64];
    __shared__ __align__(16) ushort SW[4][16][88]; // 176B rows: conflict-padded
    __shared__ float a_s[4][16], l_s[4][16];

    // ---- Q fragments in registers (lane owns q-row 16w+c, chunks g, g+4) ----
    bh8 aqu0, aqu1, aqv0, aqv1;
    {
        const ushort* qrow = qg + (size_t)(b * N_ + q0 + 16 * w + c) * QS_ + h * DK_;
        const float* buh = bu + h * DK_;
        const float* bvh = bv + h * DK_;
        bh8 qa = *(const bh8*)(qrow + g * 8);
        bh8 qb = *(const bh8*)(qrow + (g + 4) * 8);
        float4 ua0 = *(const float4*)(buh + g * 8);
        float4 ua1 = *(const float4*)(buh + g * 8 + 4);
        float4 ub0 = *(const float4*)(buh + (g + 4) * 8);
        float4 ub1 = *(const float4*)(buh + (g + 4) * 8 + 4);
        float4 va0 = *(const float4*)(bvh + g * 8);
        float4 va1 = *(const float4*)(bvh + g * 8 + 4);
        float4 vb0 = *(const float4*)(bvh + (g + 4) * 8);
        float4 vb1 = *(const float4*)(bvh + (g + 4) * 8 + 4);
        float ua[8] = {ua0.x, ua0.y, ua0.z, ua0.w, ua1.x, ua1.y, ua1.z, ua1.w};
        float ub[8] = {ub0.x, ub0.y, ub0.z, ub0.w, ub1.x, ub1.y, ub1.z, ub1.w};
        float va[8] = {va0.x, va0.y, va0.z, va0.w, va1.x, va1.y, va1.z, va1.w};
        float vb[8] = {vb0.x, vb0.y, vb0.z, vb0.w, vb1.x, vb1.y, vb1.z, vb1.w};
#pragma unroll
        for (int e = 0; e < 8; ++e) {
            float fa = bf2f((ushort)qa[e]);
            float fb = bf2f((ushort)qb[e]);
            aqu0[e] = (short)f2bf(fa + ua[e]);
            aqu1[e] = (short)f2bf(fb + ub[e]);
            aqv0[e] = (short)f2bf(fa + va[e]);
            aqv1[e] = (short)f2bf(fb + vb[e]);
        }
    }

    float m_run[4] = {-1e30f, -1e30f, -1e30f, -1e30f};
    float l_run[4] = {0.f, 0.f, 0.f, 0.f};

    f4 ctxa[4];
#pragma unroll
    for (int dt = 0; dt < 4; ++dt) ctxa[dt] = (f4){0.f, 0.f, 0.f, 0.f};

    const int str = tid >> 3;   // 0..31 (gload staging row)
    const int sch = tid & 7;

    for (int t = 0; t < 8; ++t) {
        const int k0 = t * 64;
        if (t) __syncthreads();   // prior tile's LDS reads done

        // ---- K tile via global_load_lds (pre-swizzled source) ----
#pragma unroll
        for (int i = 0; i < 2; ++i) {
            const int r = i * 32 + str;
            const ushort* src = kg + (size_t)(b * N_ + k0 + r) * QS_ + h * DK_
                                + ((sch ^ (r & 7)) * 8);
            gload_lds16(src, (char*)Kt + r * 128 + sch * 16);
        }
        // ---- P window via global_load_lds ----
        {
            const int wbase = k0 + 448 - q0;
#pragma unroll
            for (int i = 0; i < 4; ++i) {
                const int r = i * 32 + str;
                int j = wbase + r; if (j > 1022) j = 1022;
                const ushort* src = pg + (size_t)j * D_ + h * DK_
                                    + ((sch ^ (r & 7)) * 8);
                gload_lds16(src, (char*)Pt + r * 128 + sch * 16);
            }
        }
        // ---- V^T tile: wave w covers chunks w*2,w*2+1 for row = lane ----
        {
            const ushort* vrow = vg + (size_t)(b * N_ + k0 + lane) * QS_ + h * DK_;
#pragma unroll
            for (int half = 0; half < 2; ++half) {
                const int ch = w * 2 + half;
                bh8 v8 = *(const bh8*)(vrow + ch * 8);
#pragma unroll
                for (int e = 0; e < 8; ++e) {
                    const int db = ch * 8 + e;
                    Vt[db][(((lane >> 3) ^ (db & 7)) << 3) | (lane & 7)] = (ushort)v8[e];
                }
            }
        }
        __syncthreads();

        // ---- bd_tilde[q][j] = Qv . P over wave's 80-wide window ----
        const int joff = 48 - 16 * w;
#pragma unroll
        for (int jt = 0; jt < 5; ++jt) {
            const int jb = joff + jt * 16;
            bh8 p0 = LOAD8(Pt, jb + c, g);
            bh8 p1 = LOAD8(Pt, jb + c, g + 4);
            f4 acc = (f4){0.f, 0.f, 0.f, 0.f};
            acc = __builtin_amdgcn_mfma_f32_16x16x32_bf16(aqv0, p0, acc, 0, 0, 0);
            acc = __builtin_amdgcn_mfma_f32_16x16x32_bf16(aqv1, p1, acc, 0, 0, 0);
#pragma unroll
            for (int r = 0; r < 4; ++r)
                SW[w][4 * g + r][jt * 16 + c] = f2bf(acc[r]);
        }

        // ---- ac = Qu . K^T ----
        f4 S[4];
#pragma unroll
        for (int kt = 0; kt < 4; ++kt) {
            bh8 k0f = LOAD8(Kt, kt * 16 + c, g);
            bh8 k1f = LOAD8(Kt, kt * 16 + c, g + 4);
            f4 acc = (f4){0.f, 0.f, 0.f, 0.f};
            acc = __builtin_amdgcn_mfma_f32_16x16x32_bf16(aqu0, k0f, acc, 0, 0, 0);
            acc = __builtin_amdgcn_mfma_f32_16x16x32_bf16(aqu1, k1f, acc, 0, 0, 0);
            S[kt] = acc;
        }

        // ---- rel-shift apply + scale ----
#pragma unroll
        for (int kt = 0; kt < 4; ++kt)
#pragma unroll
            for (int r = 0; r < 4; ++r) {
                const int qloc = 4 * g + r;
                const int kloc = kt * 16 + c;
                S[kt][r] = (S[kt][r] + bf2f(SW[w][qloc][kloc - qloc + 15])) * 0.125f;
            }

        // ---- online softmax (m/l in registers) ----
        float mx[4], al[4];
#pragma unroll
        for (int r = 0; r < 4; ++r) {
            float t1 = fmaxf(fmaxf(S[0][r], S[1][r]), fmaxf(S[2][r], S[3][r]));
            t1 = fmaxf(t1, __shfl_xor(t1, 1));
            t1 = fmaxf(t1, __shfl_xor(t1, 2));
            t1 = fmaxf(t1, __shfl_xor(t1, 4));
            t1 = fmaxf(t1, __shfl_xor(t1, 8));
            mx[r] = t1;
        }
#pragma unroll
        for (int r = 0; r < 4; ++r) {
            float mn = fmaxf(m_run[r], mx[r]);
            al[r] = __expf(m_run[r] - mn);
            m_run[r] = mn;
        }
#pragma unroll
        for (int kt = 0; kt < 4; ++kt)
#pragma unroll
            for (int r = 0; r < 4; ++r)
                S[kt][r] = __expf(S[kt][r] - m_run[r]);
        float ts[4];
#pragma unroll
        for (int r = 0; r < 4; ++r) {
            float s1 = (S[0][r] + S[1][r]) + (S[2][r] + S[3][r]);
            s1 += __shfl_xor(s1, 1);
            s1 += __shfl_xor(s1, 2);
            s1 += __shfl_xor(s1, 4);
            s1 += __shfl_xor(s1, 8);
            ts[r] = s1;
            l_run[r] = l_run[r] * al[r] + s1;
        }
        if (c == 0) {
#pragma unroll
            for (int r = 0; r < 4; ++r) a_s[w][4 * g + r] = al[r];
        }
        // ---- P_attn (bf16) into SW cols 0..63 ----
#pragma unroll
        for (int kt = 0; kt < 4; ++kt)
#pragma unroll
            for (int r = 0; r < 4; ++r)
                SW[w][4 * g + r][kt * 16 + c] = f2bf(S[kt][r]);

        // ---- ctx^T += V^T @ P_attn^T, online rescale ----
        const float af = a_s[w][c];   // alpha of this lane's ctx column (q=c)
#pragma unroll
        for (int dt = 0; dt < 4; ++dt)
#pragma unroll
            for (int r = 0; r < 4; ++r)
                ctxa[dt][r] *= af;
#pragma unroll
        for (int kcc = 0; kcc < 2; ++kcc) {
            bh8 pb8 = *(const bh8*)&SW[w][c][(kcc * 4 + g) * 8];
#pragma unroll
            for (int dt = 0; dt < 4; ++dt) {
                bh8 av = LOAD8(Vt, dt * 16 + c, kcc * 4 + g);
                ctxa[dt] = __builtin_amdgcn_mfma_f32_16x16x32_bf16(av, pb8, ctxa[dt], 0, 0, 0);
            }
        }
    }

    // ---- epilogue: ctx[q][d] = ctx^T / l  (bf16) ----
    if (c == 0) {
#pragma unroll
        for (int r = 0; r < 4; ++r) l_s[w][4 * g + r] = l_run[r];
    }
    const float linv = 1.f / l_s[w][c];
    const int qgl = q0 + 16 * w + c;
    ushort* crow = ctx + ((size_t)(b * N_ + qgl) * D_ + h * DK_);
#pragma unroll
    for (int dt = 0; dt < 4; ++dt)
#pragma unroll
        for (int r = 0; r < 4; ++r)
            crow[dt * 16 + 4 * g + r] = f2bf(ctxa[dt][r] * linv);
}

// ---------------------------------------------------------------------------
// out = LayerNorm( sum_p parts[p] + colbias + res ) * g + beta  (+bf16 copy)
// res may alias out (per-thread load-before-store; disjoint rows per block).
// ---------------------------------------------------------------------------
template<int P>
__global__ __launch_bounds__(256)
void add_ln_kernel(const float* __restrict__ parts, size_t pstride,
                   const float* __restrict__ colbias,
                   const float* res,
                   const float* __restrict__ g, const float* __restrict__ beta,
                   float* out, ushort* __restrict__ outb)
{
    const int row = blockIdx.x;
    const int tid = threadIdx.x;
    const int lane = tid & 63, wave = tid >> 6;
    __shared__ float red[8];

    const size_t rb = (size_t)row * D_;
    float v[3];
#pragma unroll
    for (int j = 0; j < 3; ++j) {
        const int col = tid + j * 256;
        const size_t idx = rb + col;
        float s = colbias[col] + res[idx];
#pragma unroll
        for (int p = 0; p < P; ++p) s += parts[p * pstride + idx];
        v[j] = s;
    }

    float s = v[0] + v[1] + v[2];
#pragma unroll
    for (int off = 32; off; off >>= 1) s += __shfl_xor(s, off);
    if (lane == 0) red[wave] = s;
    __syncthreads();
    const float mean = (red[0] + red[1] + red[2] + red[3]) * (1.f / 768.f);

    float d0 = v[0] - mean, d1 = v[1] - mean, d2 = v[2] - mean;
    float vs = d0 * d0 + d1 * d1 + d2 * d2;
#pragma unroll
    for (int off = 32; off; off >>= 1) vs += __shfl_xor(vs, off);
    if (lane == 0) red[4 + wave] = vs;
    __syncthreads();
    const float var = (red[4] + red[5] + red[6] + red[7]) * (1.f / 768.f);
    const float inv = rsqrtf(var + 1e-5f);

    float r0 = d0 * inv * g[tid]       + beta[tid];
    float r1 = d1 * inv * g[tid + 256] + beta[tid + 256];
    float r2 = d2 * inv * g[tid + 512] + beta[tid + 512];
    float* orow = out + rb;
    orow[tid] = r0; orow[tid + 256] = r1; orow[tid + 512] = r2;
    ushort* brow = outb + rb;
    brow[tid] = f2bf(r0); brow[tid + 256] = f2bf(r1); brow[tid + 512] = f2bf(r2);
}

// ---------------------------------------------------------------------------
extern "C" void kernel_launch(void* const* d_in, const int* in_sizes, int n_in,
                              void* d_out, int out_size, void* d_ws, size_t ws_size,
                              hipStream_t stream)
{
    const float* x         = (const float*)d_in[0];
    const float* pos_emb   = (const float*)d_in[2];
    const float* residual  = (const float*)d_in[3];
    const float* fuse_W    = (const float*)d_in[5];
    const float* fuse_b    = (const float*)d_in[6];
    const float* posproj_W = (const float*)d_in[7];
    const float* posproj_b = (const float*)d_in[8];
    const float* Wq        = (const float*)d_in[9];
    const float* bq        = (const float*)d_in[10];
    const float* Wk        = (const float*)d_in[11];
    const float* bk        = (const float*)d_in[12];
    const float* Wv        = (const float*)d_in[13];
    const float* bv        = (const float*)d_in[14];
    const float* Wout      = (const float*)d_in[15];
    const float* bout      = (const float*)d_in[16];
    const float* Wpos      = (const float*)d_in[17];
    const float* pbu       = (const float*)d_in[18];
    const float* pbv       = (const float*)d_in[19];
    const float* ln1_g     = (const float*)d_in[20];
    const float* ln1_b     = (const float*)d_in[21];
    const float* Wi        = (const float*)d_in[22];
    const float* bi        = (const float*)d_in[23];
    const float* Wo        = (const float*)d_in[24];
    const float* bo        = (const float*)d_in[25];
    const float* ln2_g     = (const float*)d_in[26];
    const float* ln2_b     = (const float*)d_in[27];
    const float* Wac       = (const float*)d_in[28];
    const float* bac       = (const float*)d_in[29];

    const size_t MD = (size_t)BN_TOT * D_;

    // ---- workspace carve (bytes, 256-aligned); total ~129 MB ----
    char* base = (char*)d_ws;
    auto alloc = [&](size_t bytes) {
        char* p = base; base += (bytes + 255) & ~(size_t)255; return p;
    };
    float*  h1    = (float*) alloc(MD * 4);             // fuse-h, then LN1 out
    float*  R     = (float*) alloc(2 * MD * 4);         // split-K partials (shared)
    ushort* big   = (ushort*)alloc((size_t)BN_TOT * FF_ * 2);  // catb / ff1b
    ushort* hb    = (ushort*)alloc(MD * 2);
    ushort* qkvb  = (ushort*)alloc((size_t)BN_TOT * QS_ * 2);  // fused q|k|v
    ushort* ctxb  = (ushort*)alloc(MD * 2);
    ushort* h1b   = (ushort*)alloc(MD * 2);
    ushort* h2b   = (ushort*)alloc(MD * 2);
    ushort* peb   = (ushort*)alloc((size_t)P_ * D_ * 2);
    ushort* pbb   = (ushort*)alloc((size_t)P_ * D_ * 2);
    ushort* posb  = (ushort*)alloc((size_t)P_ * A_ * 2);
    ushort* wfuse = (ushort*)alloc((size_t)D_ * CATK * 2);
    ushort* wpp   = (ushort*)alloc((size_t)D_ * A_ * 2);
    ushort* wqkv  = (ushort*)alloc((size_t)QS_ * D_ * 2);      // Wq|Wk|Wv rows
    ushort* wout  = (ushort*)alloc((size_t)D_ * D_ * 2);
    ushort* wpos  = (ushort*)alloc((size_t)D_ * D_ * 2);
    ushort* wi    = (ushort*)alloc((size_t)FF_ * D_ * 2);
    ushort* wo    = (ushort*)alloc((size_t)D_ * FF_ * 2);
    ushort* wac   = (ushort*)alloc((size_t)A_ * D_ * 2);
    ushort* catb  = big;   // dead after fuse GEMM
    ushort* ff1b  = big;

    float* out_ac = (float*)d_out;
    float* h2     = out_ac + (size_t)BN_TOT * A_;

    dim3 blk(256);

    // ---- 0. convert weights + pos_emb to bf16 (Wq/Wk/Wv stacked = wqkv) ----
    {
        CvtJobs J;
        const float* s[11] = {fuse_W, posproj_W, Wq, Wk, Wv, Wout, Wpos, Wi, Wo, Wac, pos_emb};
        ushort* d[11] = {wfuse, wpp, wqkv, wqkv + (size_t)D_*D_, wqkv + (size_t)2*D_*D_,
                         wout, wpos, wi, wo, wac, posb};
        int n[11] = {D_*CATK, D_*A_, D_*D_, D_*D_, D_*D_, D_*D_, D_*D_, FF_*D_, D_*FF_, A_*D_, P_*A_};
        int cum = 0;
        for (int j = 0; j < 11; ++j) {
            J.src[j] = s[j]; J.dst[j] = d[j]; J.cum[j] = cum; cum += n[j] / 8;
        }
        J.cum[11] = cum;
        cvt_kernel<<<(cum + 255) / 256, blk, 0, stream>>>(J, cum);
    }
    // ---- 1. concat -> catb (bf16) ----
    concat_kernel<<<(BN_TOT * (CATK / 8) + 255) / 256, blk, 0, stream>>>(x, residual, catb);
    // ---- 2. h = cat @ fuse_W^T (split-K=2 -> R), reduce + fuse_b -> h1(f32)+hb ----
    gemm_bf16<0, true, false, 2><<<dim3(2 * (BN_TOT/128) * (D_/128)), blk, 0, stream>>>(
        catb, wfuse, nullptr, nullptr, nullptr, R, nullptr, BN_TOT, D_, CATK);
    reduce2_kernel<true, true><<<dim3((int)(MD / 8 / 256)), blk, 0, stream>>>(
        R, MD, fuse_b, D_, h1, hb, (int)(MD / 8));
    // ---- 3. pe = pos_emb @ posproj^T + b  (bf16) ----
    gemm_bf16<0, false, true, 1><<<dim3(8 * (D_/128)), blk, 0, stream>>>(
        posb, wpp, posproj_b, nullptr, nullptr, nullptr, peb, P_, D_, A_);
    // ---- 4. qkv = h @ [Wq|Wk|Wv]^T + [bq|bk|bv]  (bf16, N=2304) ----
    gemm_bf16<0, false, true, 1><<<dim3((BN_TOT/128) * (QS_/128)), blk, 0, stream>>>(
        hb, wqkv, bq, bk, bv, nullptr, qkvb, BN_TOT, QS_, D_);
    // ---- 5. p = pe @ Wpos^T  (bf16) ----
    gemm_bf16<0, false, true, 1><<<dim3(8 * (D_/128)), blk, 0, stream>>>(
        peb, wpos, nullptr, nullptr, nullptr, nullptr, pbb, P_, D_, D_);
    // ---- 6. fused attention -> ctxb (bf16) ----
    attn_mfma_kernel<<<dim3(B_ * H_ * 8), blk, 0, stream>>>(
        qkvb, pbb, pbu, pbv, ctxb);
    // ---- 7. attn_out partials = ctx @ Wout^T (split-K=2 -> R) ----
    gemm_bf16<0, true, false, 2><<<dim3(2 * (BN_TOT/128) * (D_/128)), blk, 0, stream>>>(
        ctxb, wout, nullptr, nullptr, nullptr, R, nullptr, BN_TOT, D_, D_);
    // ---- 8. h1 = LN(R0+R1+bout + h1)  (res aliases out; safe) ----
    add_ln_kernel<2><<<BN_TOT, blk, 0, stream>>>(R, MD, bout, h1, ln1_g, ln1_b, h1, h1b);
    // ---- 9. ff1 = gelu(h1 @ Wi^T + bi)  (bf16) ----
    gemm_bf16<1, false, true, 1><<<dim3((BN_TOT/128) * (FF_/128)), blk, 0, stream>>>(
        h1b, wi, bi, nullptr, nullptr, nullptr, ff1b, BN_TOT, FF_, D_);
    // ---- 10. ff2 partials = ff1 @ Wo^T (split-K=2 -> R) ----
    gemm_bf16<0, true, false, 2><<<dim3(2 * (BN_TOT/128) * (D_/128)), blk, 0, stream>>>(
        ff1b, wo, nullptr, nullptr, nullptr, R, nullptr, BN_TOT, D_, FF_);
    // ---- 11. h2 = LN(R0+R1+bo + h1) -> d_out (+bf16) ----
    add_ln_kernel<2><<<BN_TOT, blk, 0, stream>>>(R, MD, bo, h1, ln2_g, ln2_b, h2, h2b);
    // ---- 12. out_ac partials = h2 @ Wac^T (split-K=2 -> R), reduce + bac ----
    gemm_bf16<0, true, false, 2><<<dim3(2 * (BN_TOT/128) * (A_/128)), blk, 0, stream>>>(
        h2b, wac, nullptr, nullptr, nullptr, R, nullptr, BN_TOT, A_, D_);
    reduce2_kernel<true, false><<<dim3((int)((size_t)BN_TOT * A_ / 8 / 256)), blk, 0, stream>>>(
        R, (size_t)BN_TOT * A_, bac, A_, out_ac, nullptr, (int)((size_t)BN_TOT * A_ / 8));
}